// Round 8
// baseline (148.980 us; speedup 1.0000x reference)
//
#include <hip/hip_runtime.h>
#include <math.h>

#define C_DIM 1024
#define B_SZ 2
#define N_SEQ 2048
#define M_ROWS (B_SZ * N_SEQ)   // 4096
#define KDIM 1024
#define SLOT_EL 16384           // ushort elements per 32KB gemm1 slot
#define SLOT2_EL 8192           // ushort elements per 16KB gemm2 slot

typedef float  f32x4   __attribute__((ext_vector_type(4)));
typedef short  bf16x8  __attribute__((ext_vector_type(8)));
typedef short  short4v __attribute__((ext_vector_type(4)));
typedef short  short8v __attribute__((ext_vector_type(8)));

__device__ __forceinline__ float elu1(float v) {
    return v > 0.f ? v + 1.f : expf(v);
}

__device__ __forceinline__ ushort f2bf(float f) {
    union { float f; unsigned u; } x; x.f = f;
    unsigned r = (x.u + 0x7fffu + ((x.u >> 16) & 1u)) >> 16;  // RNE
    return (ushort)r;
}
__device__ __forceinline__ float bf2f(ushort b) {
    union { unsigned u; float f; } x; x.u = ((unsigned)b) << 16;
    return x.f;
}

#define VMCNT(n) asm volatile("s_waitcnt vmcnt(" #n ")" ::: "memory")
#define LGKM0    do { asm volatile("s_waitcnt lgkmcnt(0)" ::: "memory"); \
                      __builtin_amdgcn_sched_barrier(0); } while (0)
#define BAR      __builtin_amdgcn_s_barrier()

__device__ __forceinline__ void gl16(const ushort* g, ushort* l) {
    __builtin_amdgcn_global_load_lds(
        (const __attribute__((address_space(1))) unsigned int*)g,
        (__attribute__((address_space(3))) unsigned int*)l,
        16, 0, 0);
}

// ---------------------------------------------------------------------------
// fp32 -> bf16 hi/lo split for all 4 inputs in one launch. 8 elems/thread.
// ---------------------------------------------------------------------------
__global__ __launch_bounds__(256)
void split_all_kernel(const float* __restrict__ x, const float* __restrict__ Wq,
                      const float* __restrict__ Wkv, const float* __restrict__ Wo,
                      ushort* __restrict__ xhi, ushort* __restrict__ xlo,
                      ushort* __restrict__ Whi, ushort* __restrict__ Wlo,
                      ushort* __restrict__ Wohi, ushort* __restrict__ Wolo)
{
    const int i = blockIdx.x * 256 + threadIdx.x;   // 0..1048575
    const float* src; ushort* dh; ushort* dl; int off;
    if (i < 524288)        { src = x;   dh = xhi;  dl = xlo;  off = i; }
    else if (i < 655360)   { src = Wq;  dh = Whi;  dl = Wlo;  off = i - 524288; }
    else if (i < 917504)   { src = Wkv; dh = Whi + (1u << 20); dl = Wlo + (1u << 20); off = i - 655360; }
    else                   { src = Wo;  dh = Wohi; dl = Wolo; off = i - 917504; }

    const float4 a = ((const float4*)src)[off * 2];
    const float4 b = ((const float4*)src)[off * 2 + 1];
    const float v[8] = {a.x, a.y, a.z, a.w, b.x, b.y, b.z, b.w};
    ushort hv[8], lv[8];
    #pragma unroll
    for (int j = 0; j < 8; ++j) {
        hv[j] = f2bf(v[j]);
        lv[j] = f2bf(v[j] - bf2f(hv[j]));
    }
    short8v H = {(short)hv[0],(short)hv[1],(short)hv[2],(short)hv[3],
                 (short)hv[4],(short)hv[5],(short)hv[6],(short)hv[7]};
    short8v L = {(short)lv[0],(short)lv[1],(short)lv[2],(short)lv[3],
                 (short)lv[4],(short)lv[5],(short)lv[6],(short)lv[7]};
    *(short8v*)&dh[(size_t)off * 8] = H;
    *(short8v*)&dl[(size_t)off * 8] = L;
}

// ---------------------------------------------------------------------------
// GEMM1: QKV = [x][Wq;Wkv]^T, 3-term split-bf16, 256x192 tile, BK=32,
// mfma_f32_16x16x32_bf16. 8 waves (2M x 4N), wave tile 128x48. Grid 256
// (full fill). 3-phase / 2-barrier-per-kt schedule:
//   ph1: vm(4) BAR | stage next-hi | read hi frags | lgkm0 | 24 MFMA hh
//   ph2: vm(4) BAR | stage next-lo | read lo frags | lgkm0 | 24 MFMA hl
//   ph3: 24 MFMA lh (register-only, no barrier)
// Slot safety: slot staged at kt+1-ph1 was last read at kt-ph1; all waves
// pass kt-ph2 BAR (post-reads) before any kt+1 staging issues.
// ---------------------------------------------------------------------------
__global__ __launch_bounds__(512, 2)
void gemm1_mfma256_kernel(const ushort* __restrict__ Ahi, const ushort* __restrict__ Alo,
                          const ushort* __restrict__ Bhi, const ushort* __restrict__ Blo,
                          float* __restrict__ dst)
{
    extern __shared__ ushort smem[];   // 4 slots x 16384 ushorts (128 KB)

    const int bid = blockIdx.x;
    const int wg  = (bid & 7) * 32 + (bid >> 3);    // bijective: 256 = 8*32
    const int m0  = (wg >> 4) * 256;
    const int n0  = (wg & 15) * 192;

    const int t    = threadIdx.x;
    const int lane = t & 63;
    const int w    = t >> 6;
    const int wr   = w >> 2;       // 0..1
    const int wc   = w & 3;        // 0..3

    const int gch     = (t & 3) ^ ((t >> 3) & 3);
    const size_t rowA  = (size_t)(m0 + (t >> 2)) * KDIM + gch * 8;
    const size_t rowA2 = rowA + (size_t)128 * KDIM;
    const size_t rowB  = (size_t)(n0 + (t >> 2)) * KDIM + gch * 8;
    const int    bclmp = (n0 + (t >> 2) + 128 < 3072) ? (n0 + (t >> 2) + 128) : 3071;
    const size_t rowB2 = (size_t)bclmp * KDIM + gch * 8;
    const int wl      = w * 512;

    const int frow = lane & 15;
    const int cc   = (lane >> 4) ^ ((lane >> 1) & 3);
    const int aoff = (wr * 128 + frow) * 32 + cc * 8;
    const int boff = 8192 + (wc * 48 + frow) * 32 + cc * 8;

    f32x4 acc[8][3];
    #pragma unroll
    for (int mi = 0; mi < 8; ++mi)
        #pragma unroll
        for (int nj = 0; nj < 3; ++nj)
            acc[mi][nj] = (f32x4){0.f, 0.f, 0.f, 0.f};

    #define STAGE_A(src, slotp, koff)                                        \
        do {                                                                 \
            ushort* sl_ = (slotp);                                           \
            gl16((src) + rowA  + (koff), sl_ + wl);                          \
            gl16((src) + rowA2 + (koff), sl_ + 4096 + wl);                   \
        } while (0)
    #define STAGE_B(src, slotp, koff)                                        \
        do {                                                                 \
            ushort* sl_ = (slotp);                                           \
            gl16((src) + rowB  + (koff), sl_ + 8192 + wl);                   \
            gl16((src) + rowB2 + (koff), sl_ + 12288 + wl);                  \
        } while (0)

    STAGE_A(Ahi, smem, 0);
    STAGE_B(Bhi, smem, 0);
    STAGE_A(Alo, smem + SLOT_EL, 0);
    STAGE_B(Blo, smem + SLOT_EL, 0);

    #pragma unroll 1
    for (int kt = 0; kt < 32; ++kt) {
        ushort* sh = smem + ((kt & 1) << 1) * SLOT_EL;
        ushort* sl = sh + SLOT_EL;
        ushort* nh = smem + ((2 * kt + 2) & 3) * SLOT_EL;
        ushort* nl = smem + ((2 * kt + 3) & 3) * SLOT_EL;
        const int kn = (kt + 1) * 32;

        bf16x8 ah[8], bh[3], bl[3], al[8];

        // ---- ph1: hi slot valid
        VMCNT(4);
        BAR;
        if (kt < 31) { STAGE_A(Ahi, nh, kn); STAGE_B(Bhi, nh, kn); }
        #pragma unroll
        for (int mi = 0; mi < 8; ++mi)
            ah[mi] = *(const bf16x8*)(sh + aoff + mi * 512);
        #pragma unroll
        for (int nj = 0; nj < 3; ++nj)
            bh[nj] = *(const bf16x8*)(sh + boff + nj * 512);
        LGKM0;
        __builtin_amdgcn_s_setprio(1);
        #pragma unroll
        for (int mi = 0; mi < 8; ++mi)
            #pragma unroll
            for (int nj = 0; nj < 3; ++nj)
                acc[mi][nj] = __builtin_amdgcn_mfma_f32_16x16x32_bf16(
                    ah[mi], bh[nj], acc[mi][nj], 0, 0, 0);
        __builtin_amdgcn_s_setprio(0);

        // ---- ph2: lo slot valid
        if (kt < 31) { VMCNT(4); } else { VMCNT(0); }
        BAR;
        if (kt < 31) { STAGE_A(Alo, nl, kn); STAGE_B(Blo, nl, kn); }
        #pragma unroll
        for (int nj = 0; nj < 3; ++nj)
            bl[nj] = *(const bf16x8*)(sl + boff + nj * 512);
        #pragma unroll
        for (int mi = 0; mi < 8; ++mi)
            al[mi] = *(const bf16x8*)(sl + aoff + mi * 512);
        LGKM0;
        __builtin_amdgcn_s_setprio(1);
        #pragma unroll
        for (int mi = 0; mi < 8; ++mi)
            #pragma unroll
            for (int nj = 0; nj < 3; ++nj)
                acc[mi][nj] = __builtin_amdgcn_mfma_f32_16x16x32_bf16(
                    ah[mi], bl[nj], acc[mi][nj], 0, 0, 0);
        __builtin_amdgcn_s_setprio(0);

        // ---- ph3: register-only
        __builtin_amdgcn_s_setprio(1);
        #pragma unroll
        for (int mi = 0; mi < 8; ++mi)
            #pragma unroll
            for (int nj = 0; nj < 3; ++nj)
                acc[mi][nj] = __builtin_amdgcn_mfma_f32_16x16x32_bf16(
                    al[mi], bh[nj], acc[mi][nj], 0, 0, 0);
        __builtin_amdgcn_s_setprio(0);
    }
    #undef STAGE_A
    #undef STAGE_B

    const int erow  = m0 + wr * 128 + (lane >> 4) * 4;
    const int ecol0 = n0 + wc * 48 + frow;
    #pragma unroll
    for (int mi = 0; mi < 8; ++mi) {
        #pragma unroll
        for (int j = 0; j < 4; ++j) {
            const int row = erow + mi * 16 + j;
            #pragma unroll
            for (int nj = 0; nj < 3; ++nj) {
                const int col = ecol0 + nj * 16;
                float v = acc[mi][nj][j];
                if (col < 2048) v = elu1(v);
                dst[(size_t)row * 3072 + col] = v;
            }
        }
    }
}

// ---------------------------------------------------------------------------
// GEMM2: out = O1 @ Wo^T + bo. 128x128 tile, BK=32, 4 waves (2x2, 64x64/wave),
// same 3-phase / 2-barrier-per-kt schedule. Grid 256 full fill, 64KB LDS.
// ---------------------------------------------------------------------------
__global__ __launch_bounds__(256, 2)
void gemm2_mfma_kernel(const ushort* __restrict__ Ahi, const ushort* __restrict__ Alo,
                       const ushort* __restrict__ Bhi, const ushort* __restrict__ Blo,
                       const float* __restrict__ bias, float* __restrict__ dst)
{
    __shared__ ushort smem[4 * SLOT2_EL];   // 64 KB

    const int bid = blockIdx.x;
    const int wg  = (bid & 7) * 32 + (bid >> 3);    // bijective: 256 = 8*32
    const int m0  = (wg >> 3) * 128;                // 32 m-tiles
    const int n0  = (wg & 7) * 128;                 // 8 n-tiles

    const int t    = threadIdx.x;
    const int lane = t & 63;
    const int w    = t >> 6;      // 0..3
    const int wr   = w >> 1;      // 0..1
    const int wc   = w & 1;       // 0..1

    const int gch     = (t & 3) ^ ((t >> 3) & 3);
    const size_t rowA = (size_t)(m0 + (t >> 2)) * KDIM + gch * 8;
    const size_t rowB = (size_t)(n0 + (t >> 2)) * KDIM + gch * 8;
    const int wl      = w * 512;

    const int frow = lane & 15;
    const int cc   = (lane >> 4) ^ ((lane >> 1) & 3);
    const int aoff = (wr * 64 + frow) * 32 + cc * 8;
    const int boff = 4096 + (wc * 64 + frow) * 32 + cc * 8;

    f32x4 acc[4][4];
    #pragma unroll
    for (int mi = 0; mi < 4; ++mi)
        #pragma unroll
        for (int nj = 0; nj < 4; ++nj)
            acc[mi][nj] = (f32x4){0.f, 0.f, 0.f, 0.f};

    #define G2A(src, slotp, koff)                                            \
        do {                                                                 \
            ushort* p_ = (slotp);                                            \
            gl16((src) + rowA + (koff),         p_ + wl);                    \
            gl16((src) + rowA + 65536 + (koff), p_ + 2048 + wl);             \
        } while (0)
    #define G2B(src, slotp, koff)                                            \
        do {                                                                 \
            ushort* p_ = (slotp);                                            \
            gl16((src) + rowB + (koff),         p_ + 4096 + wl);             \
            gl16((src) + rowB + 65536 + (koff), p_ + 6144 + wl);             \
        } while (0)

    G2A(Ahi, smem, 0);
    G2B(Bhi, smem, 0);
    G2A(Alo, smem + SLOT2_EL, 0);
    G2B(Blo, smem + SLOT2_EL, 0);

    #pragma unroll 1
    for (int kt = 0; kt < 32; ++kt) {
        ushort* sh = smem + ((kt & 1) << 1) * SLOT2_EL;
        ushort* sl = sh + SLOT2_EL;
        ushort* nh = smem + ((2 * kt + 2) & 3) * SLOT2_EL;
        ushort* nl = smem + ((2 * kt + 3) & 3) * SLOT2_EL;
        const int kn = (kt + 1) * 32;

        bf16x8 ah[4], bh[4], bl[4], al[4];

        // ---- ph1: hh
        VMCNT(4);
        BAR;
        if (kt < 31) { G2A(Ahi, nh, kn); G2B(Bhi, nh, kn); }
        #pragma unroll
        for (int mi = 0; mi < 4; ++mi)
            ah[mi] = *(const bf16x8*)(sh + aoff + mi * 512);
        #pragma unroll
        for (int nj = 0; nj < 4; ++nj)
            bh[nj] = *(const bf16x8*)(sh + boff + nj * 512);
        LGKM0;
        __builtin_amdgcn_s_setprio(1);
        #pragma unroll
        for (int mi = 0; mi < 4; ++mi)
            #pragma unroll
            for (int nj = 0; nj < 4; ++nj)
                acc[mi][nj] = __builtin_amdgcn_mfma_f32_16x16x32_bf16(
                    ah[mi], bh[nj], acc[mi][nj], 0, 0, 0);
        __builtin_amdgcn_s_setprio(0);

        // ---- ph2: hl
        if (kt < 31) { VMCNT(4); } else { VMCNT(0); }
        BAR;
        if (kt < 31) { G2A(Alo, nl, kn); G2B(Blo, nl, kn); }
        #pragma unroll
        for (int nj = 0; nj < 4; ++nj)
            bl[nj] = *(const bf16x8*)(sl + boff + nj * 512);
        #pragma unroll
        for (int mi = 0; mi < 4; ++mi)
            al[mi] = *(const bf16x8*)(sl + aoff + mi * 512);
        LGKM0;
        __builtin_amdgcn_s_setprio(1);
        #pragma unroll
        for (int mi = 0; mi < 4; ++mi)
            #pragma unroll
            for (int nj = 0; nj < 4; ++nj)
                acc[mi][nj] = __builtin_amdgcn_mfma_f32_16x16x32_bf16(
                    ah[mi], bl[nj], acc[mi][nj], 0, 0, 0);
        __builtin_amdgcn_s_setprio(0);

        // ---- ph3: lh (register-only)
        __builtin_amdgcn_s_setprio(1);
        #pragma unroll
        for (int mi = 0; mi < 4; ++mi)
            #pragma unroll
            for (int nj = 0; nj < 4; ++nj)
                acc[mi][nj] = __builtin_amdgcn_mfma_f32_16x16x32_bf16(
                    al[mi], bh[nj], acc[mi][nj], 0, 0, 0);
        __builtin_amdgcn_s_setprio(0);
    }
    #undef G2A
    #undef G2B

    const int erow  = m0 + wr * 64 + (lane >> 4) * 4;
    const int ecol0 = n0 + wc * 64 + frow;
    #pragma unroll
    for (int mi = 0; mi < 4; ++mi) {
        #pragma unroll
        for (int j = 0; j < 4; ++j) {
            const int row = erow + mi * 16 + j;
            #pragma unroll
            for (int nj = 0; nj < 4; ++nj) {
                const int col = ecol0 + nj * 16;
                dst[(size_t)row * 1024 + col] = acc[mi][nj][j] + bias[col];
            }
        }
    }
}

// ---------------------------------------------------------------------------
// Partial KV = K_feat^T V and ksum, per (b,h), 8-way N split (256 rows each).
// ---------------------------------------------------------------------------
__global__ __launch_bounds__(256)
void kv_partial_kernel(const float* __restrict__ QKV, float* __restrict__ KVp)
{
    const int bh = blockIdx.x;   // 0..31
    const int s  = blockIdx.y;   // 0..7
    const int b  = bh >> 4;
    const int h  = bh & 15;
    const int t  = threadIdx.x;

    __shared__ float ks[16][64];
    __shared__ float vs[16][64];
    __shared__ float red[4160];

    const int srow = t >> 4;
    const int scol = (t & 15) * 4;
    const size_t gk = (size_t)(b * N_SEQ + s * 256) * 3072 + 1024 + h * 64 + scol;
    const size_t gv = gk + 1024;

    const int rs = t >> 6;
    const int dg = (t >> 3) & 7;
    const int eg = t & 7;
    const int d0 = dg * 8;
    const int e0 = eg * 8;

    float acc[8][8];
    #pragma unroll
    for (int i = 0; i < 8; ++i)
        #pragma unroll
        for (int j = 0; j < 8; ++j) acc[i][j] = 0.f;
    float aks[8] = {0.f, 0.f, 0.f, 0.f, 0.f, 0.f, 0.f, 0.f};

    float4 kr = *(const float4*)&QKV[gk + (size_t)srow * 3072];
    float4 vr = *(const float4*)&QKV[gv + (size_t)srow * 3072];

    for (int it = 0; it < 16; ++it) {
        __syncthreads();
        *(float4*)&ks[srow][scol] = kr;
        *(float4*)&vs[srow][scol] = vr;
        __syncthreads();
        if (it < 15) {
            kr = *(const float4*)&QKV[gk + (size_t)((it + 1) * 16 + srow) * 3072];
            vr = *(const float4*)&QKV[gv + (size_t)((it + 1) * 16 + srow) * 3072];
        }
        #pragma unroll
        for (int rr = 0; rr < 4; ++rr) {
            const int r = rs * 4 + rr;
            const float4 ka = *(const float4*)&ks[r][d0];
            const float4 kb = *(const float4*)&ks[r][d0 + 4];
            const float4 va = *(const float4*)&vs[r][e0];
            const float4 vb = *(const float4*)&vs[r][e0 + 4];
            const float k8[8] = {ka.x, ka.y, ka.z, ka.w, kb.x, kb.y, kb.z, kb.w};
            const float v8[8] = {va.x, va.y, va.z, va.w, vb.x, vb.y, vb.z, vb.w};
            #pragma unroll
            for (int i = 0; i < 8; ++i)
                #pragma unroll
                for (int j = 0; j < 8; ++j)
                    acc[i][j] += k8[i] * v8[j];
            if (eg == 0) {
                #pragma unroll
                for (int i = 0; i < 8; ++i) aks[i] += k8[i];
            }
        }
    }

    #pragma unroll 1
    for (int step = 1; step < 4; ++step) {
        __syncthreads();
        if (rs == step) {
            #pragma unroll
            for (int i = 0; i < 8; ++i)
                #pragma unroll
                for (int j = 0; j < 8; ++j)
                    red[(d0 + i) * 64 + e0 + j] = acc[i][j];
            if (eg == 0) {
                #pragma unroll
                for (int i = 0; i < 8; ++i) red[4096 + d0 + i] = aks[i];
            }
        }
        __syncthreads();
        if (rs == 0) {
            #pragma unroll
            for (int i = 0; i < 8; ++i)
                #pragma unroll
                for (int j = 0; j < 8; ++j)
                    acc[i][j] += red[(d0 + i) * 64 + e0 + j];
            if (eg == 0) {
                #pragma unroll
                for (int i = 0; i < 8; ++i) aks[i] += red[4096 + d0 + i];
            }
        }
    }

    if (rs == 0) {
        float* outp = KVp + ((size_t)s * 32 + bh) * 4160;
        #pragma unroll
        for (int i = 0; i < 8; ++i) {
            float4 o0 = {acc[i][0], acc[i][1], acc[i][2], acc[i][3]};
            float4 o1 = {acc[i][4], acc[i][5], acc[i][6], acc[i][7]};
            *(float4*)(outp + (d0 + i) * 64 + e0)     = o0;
            *(float4*)(outp + (d0 + i) * 64 + e0 + 4) = o1;
        }
        if (eg == 0) {
            #pragma unroll
            for (int i = 0; i < 8; ++i) outp[4096 + d0 + i] = aks[i];
        }
    }
}

__global__ __launch_bounds__(256)
void kv_reduce_kernel(const float* __restrict__ KVp, float* __restrict__ KVf)
{
    const int idx = blockIdx.x * 256 + threadIdx.x;
    if (idx < 32 * 4160) {
        float s = 0.f;
        #pragma unroll
        for (int i = 0; i < 8; ++i) s += KVp[(size_t)i * (32 * 4160) + idx];
        KVf[idx] = s;
    }
}

// ---------------------------------------------------------------------------
// O1[n, h*64+e] = Z * sum_d q[n,d]*KV[d,e], Z = 1/(q.ksum + 1e-6); bf16 hi/lo out
// ---------------------------------------------------------------------------
__global__ __launch_bounds__(256)
void attn_apply_kernel(const float* __restrict__ QKV, const float* __restrict__ KVf,
                       ushort* __restrict__ O1hi, ushort* __restrict__ O1lo)
{
    const int bh = blockIdx.x;
    const int b = bh >> 4, h = bh & 15;
    const int n0 = blockIdx.y * 16;
    const int t = threadIdx.x;
    const int r  = t >> 4;
    const int e0 = (t & 15) * 4;

    __shared__ float kvs[64][68];
    __shared__ float qs[16][68];
    __shared__ float ksums[64];

    const float* kvb = KVf + (size_t)bh * 4160;
    for (int i = t; i < 4096; i += 256)
        kvs[i >> 6][i & 63] = kvb[i];
    if (t < 64) ksums[t] = kvb[4096 + t];
    {
        const int rr = t >> 4, cc2 = (t & 15) * 4;
        *(float4*)&qs[rr][cc2] =
            *(const float4*)&QKV[(size_t)(b * N_SEQ + n0 + rr) * 3072 + h * 64 + cc2];
    }
    __syncthreads();

    float4 acc = {0.f, 0.f, 0.f, 0.f};
    float accz = 0.f;
    #pragma unroll
    for (int d = 0; d < 64; ++d) {
        const float qv = qs[r][d];
        const float4 kvv = *(const float4*)&kvs[d][e0];
        acc.x += qv * kvv.x; acc.y += qv * kvv.y;
        acc.z += qv * kvv.z; acc.w += qv * kvv.w;
        accz += qv * ksums[d];
    }
    const float Z = 1.f / (accz + 1e-6f);
    const float vv[4] = {acc.x * Z, acc.y * Z, acc.z * Z, acc.w * Z};
    ushort hv[4], lv[4];
    #pragma unroll
    for (int j = 0; j < 4; ++j) {
        hv[j] = f2bf(vv[j]);
        lv[j] = f2bf(vv[j] - bf2f(hv[j]));
    }
    const size_t off = (size_t)(b * N_SEQ + n0 + r) * C_DIM + h * 64 + e0;
    short4v H = {(short)hv[0], (short)hv[1], (short)hv[2], (short)hv[3]};
    short4v L = {(short)lv[0], (short)lv[1], (short)lv[2], (short)lv[3]};
    *(short4v*)&O1hi[off] = H;
    *(short4v*)&O1lo[off] = L;
}

extern "C" void kernel_launch(void* const* d_in, const int* in_sizes, int n_in,
                              void* d_out, int out_size, void* d_ws, size_t ws_size,
                              hipStream_t stream)
{
    const float* x   = (const float*)d_in[0];
    const float* Wq  = (const float*)d_in[1];
    const float* Wkv = (const float*)d_in[2];
    const float* Wo  = (const float*)d_in[3];
    const float* bo  = (const float*)d_in[4];
    float* out = (float*)d_out;

    float* ws   = (float*)d_ws;
    float* QKV  = ws;                                  // 4096*3072 f32
    float* KVp  = QKV + (size_t)M_ROWS * 3072;         // 8*32*4160
    float* KVf  = KVp + (size_t)8 * 32 * 4160;         // 32*4160
    ushort* xhi = (ushort*)(KVf + 32 * 4160);          // 4096*1024 bf16 each
    ushort* xlo = xhi + (size_t)M_ROWS * 1024;
    ushort* Whi = xlo + (size_t)M_ROWS * 1024;         // 3072*1024 (Wq;Wkv)
    ushort* Wlo = Whi + (size_t)3072 * 1024;
    ushort* Wohi = Wlo + (size_t)3072 * 1024;          // 1024*1024
    ushort* Wolo = Wohi + (size_t)1024 * 1024;
    ushort* O1hi = xhi;                                // alias: x dead after GEMM1
    ushort* O1lo = xlo;

    hipFuncSetAttribute((const void*)gemm1_mfma256_kernel,
                        hipFuncAttributeMaxDynamicSharedMemorySize, 131072);

    // 0. split fp32 -> bf16 hi/lo
    split_all_kernel<<<dim3(4096), 256, 0, stream>>>(
        x, Wq, Wkv, Wo, xhi, xlo, Whi, Wlo, Wohi, Wolo);

    // 1. fused q/k/v projections + elu+1 on q,k
    gemm1_mfma256_kernel<<<dim3(256), 512, 131072, stream>>>(xhi, xlo, Whi, Wlo, QKV);

    // 2-3. KV = K^T V + ksum (8-way split + deterministic reduce)
    kv_partial_kernel<<<dim3(32, 8), 256, 0, stream>>>(QKV, KVp);
    kv_reduce_kernel<<<dim3((32 * 4160 + 255) / 256), 256, 0, stream>>>(KVp, KVf);

    // 4. O1 = Z * (q @ KV), bf16 hi/lo out
    attn_apply_kernel<<<dim3(32, 128), 256, 0, stream>>>(QKV, KVf, O1hi, O1lo);

    // 5. final projection + bias
    gemm2_mfma_kernel<<<dim3(256), 256, 0, stream>>>(O1hi, O1lo, Wohi, Wolo, bo, out);
}

// Round 9
// 148.781 us; speedup vs baseline: 1.0013x; 1.0013x over previous
//
#include <hip/hip_runtime.h>
#include <math.h>

#define C_DIM 1024
#define B_SZ 2
#define N_SEQ 2048
#define M_ROWS (B_SZ * N_SEQ)   // 4096
#define KDIM 1024
#define SLOT_EL 16384           // ushort elements per 32KB gemm1 slot
#define SLOT2_EL 8192           // ushort elements per 16KB gemm2 slot

typedef float  f32x4   __attribute__((ext_vector_type(4)));
typedef short  bf16x8  __attribute__((ext_vector_type(8)));
typedef short  short4v __attribute__((ext_vector_type(4)));
typedef short  short8v __attribute__((ext_vector_type(8)));

__device__ __forceinline__ float elu1(float v) {
    return v > 0.f ? v + 1.f : expf(v);
}

__device__ __forceinline__ ushort f2bf(float f) {
    union { float f; unsigned u; } x; x.f = f;
    unsigned r = (x.u + 0x7fffu + ((x.u >> 16) & 1u)) >> 16;  // RNE
    return (ushort)r;
}
__device__ __forceinline__ float bf2f(ushort b) {
    union { unsigned u; float f; } x; x.u = ((unsigned)b) << 16;
    return x.f;
}

#define VMCNT(n) asm volatile("s_waitcnt vmcnt(" #n ")" ::: "memory")
#define BAR      __builtin_amdgcn_s_barrier()

__device__ __forceinline__ void gl16(const ushort* g, ushort* l) {
    __builtin_amdgcn_global_load_lds(
        (const __attribute__((address_space(1))) unsigned int*)g,
        (__attribute__((address_space(3))) unsigned int*)l,
        16, 0, 0);
}

// ---------------------------------------------------------------------------
// fp32 -> bf16 hi/lo split for all 4 inputs in one launch. 8 elems/thread.
// ---------------------------------------------------------------------------
__global__ __launch_bounds__(256)
void split_all_kernel(const float* __restrict__ x, const float* __restrict__ Wq,
                      const float* __restrict__ Wkv, const float* __restrict__ Wo,
                      ushort* __restrict__ xhi, ushort* __restrict__ xlo,
                      ushort* __restrict__ Whi, ushort* __restrict__ Wlo,
                      ushort* __restrict__ Wohi, ushort* __restrict__ Wolo)
{
    const int i = blockIdx.x * 256 + threadIdx.x;   // 0..1048575
    const float* src; ushort* dh; ushort* dl; int off;
    if (i < 524288)        { src = x;   dh = xhi;  dl = xlo;  off = i; }
    else if (i < 655360)   { src = Wq;  dh = Whi;  dl = Wlo;  off = i - 524288; }
    else if (i < 917504)   { src = Wkv; dh = Whi + (1u << 20); dl = Wlo + (1u << 20); off = i - 655360; }
    else                   { src = Wo;  dh = Wohi; dl = Wolo; off = i - 917504; }

    const float4 a = ((const float4*)src)[off * 2];
    const float4 b = ((const float4*)src)[off * 2 + 1];
    const float v[8] = {a.x, a.y, a.z, a.w, b.x, b.y, b.z, b.w};
    ushort hv[8], lv[8];
    #pragma unroll
    for (int j = 0; j < 8; ++j) {
        hv[j] = f2bf(v[j]);
        lv[j] = f2bf(v[j] - bf2f(hv[j]));
    }
    short8v H = {(short)hv[0],(short)hv[1],(short)hv[2],(short)hv[3],
                 (short)hv[4],(short)hv[5],(short)hv[6],(short)hv[7]};
    short8v L = {(short)lv[0],(short)lv[1],(short)lv[2],(short)lv[3],
                 (short)lv[4],(short)lv[5],(short)lv[6],(short)lv[7]};
    *(short8v*)&dh[(size_t)off * 8] = H;
    *(short8v*)&dl[(size_t)off * 8] = L;
}

// ---------------------------------------------------------------------------
// GEMM1: QKV = [x][Wq;Wkv]^T, 3-term split-bf16, 256x192 tile, BK=32,
// mfma_f32_16x16x32_bf16. 8 waves (2M x 4N), wave tile 128x48. Grid 256
// (full fill). 3-phase / 2-barrier-per-kt schedule; NO manual lgkm fence —
// ds_reads are plain loads, the compiler inserts precise per-operand
// lgkmcnt waits and interleaves MFMA with outstanding reads.
// ---------------------------------------------------------------------------
__global__ __launch_bounds__(512, 2)
void gemm1_mfma256_kernel(const ushort* __restrict__ Ahi, const ushort* __restrict__ Alo,
                          const ushort* __restrict__ Bhi, const ushort* __restrict__ Blo,
                          float* __restrict__ dst)
{
    extern __shared__ ushort smem[];   // 4 slots x 16384 ushorts (128 KB)

    const int bid = blockIdx.x;
    const int wg  = (bid & 7) * 32 + (bid >> 3);    // bijective: 256 = 8*32
    const int m0  = (wg >> 4) * 256;
    const int n0  = (wg & 15) * 192;

    const int t    = threadIdx.x;
    const int lane = t & 63;
    const int w    = t >> 6;
    const int wr   = w >> 2;       // 0..1
    const int wc   = w & 3;        // 0..3

    const int gch     = (t & 3) ^ ((t >> 3) & 3);
    const size_t rowA  = (size_t)(m0 + (t >> 2)) * KDIM + gch * 8;
    const size_t rowA2 = rowA + (size_t)128 * KDIM;
    const size_t rowB  = (size_t)(n0 + (t >> 2)) * KDIM + gch * 8;
    const int    bclmp = (n0 + (t >> 2) + 128 < 3072) ? (n0 + (t >> 2) + 128) : 3071;
    const size_t rowB2 = (size_t)bclmp * KDIM + gch * 8;
    const int wl      = w * 512;

    const int frow = lane & 15;
    const int cc   = (lane >> 4) ^ ((lane >> 1) & 3);
    const int aoff = (wr * 128 + frow) * 32 + cc * 8;
    const int boff = 8192 + (wc * 48 + frow) * 32 + cc * 8;

    f32x4 acc[8][3];
    #pragma unroll
    for (int mi = 0; mi < 8; ++mi)
        #pragma unroll
        for (int nj = 0; nj < 3; ++nj)
            acc[mi][nj] = (f32x4){0.f, 0.f, 0.f, 0.f};

    #define STAGE_A(src, slotp, koff)                                        \
        do {                                                                 \
            ushort* sl_ = (slotp);                                           \
            gl16((src) + rowA  + (koff), sl_ + wl);                          \
            gl16((src) + rowA2 + (koff), sl_ + 4096 + wl);                   \
        } while (0)
    #define STAGE_B(src, slotp, koff)                                        \
        do {                                                                 \
            ushort* sl_ = (slotp);                                           \
            gl16((src) + rowB  + (koff), sl_ + 8192 + wl);                   \
            gl16((src) + rowB2 + (koff), sl_ + 12288 + wl);                  \
        } while (0)

    STAGE_A(Ahi, smem, 0);
    STAGE_B(Bhi, smem, 0);
    STAGE_A(Alo, smem + SLOT_EL, 0);
    STAGE_B(Blo, smem + SLOT_EL, 0);

    #pragma unroll 1
    for (int kt = 0; kt < 32; ++kt) {
        ushort* sh = smem + ((kt & 1) << 1) * SLOT_EL;
        ushort* sl = sh + SLOT_EL;
        ushort* nh = smem + ((2 * kt + 2) & 3) * SLOT_EL;
        ushort* nl = smem + ((2 * kt + 3) & 3) * SLOT_EL;
        const int kn = (kt + 1) * 32;

        bf16x8 ah[8], bh[3], bl[3], al[8];

        // ---- ph1: hi slot valid
        VMCNT(4);
        BAR;
        if (kt < 31) { STAGE_A(Ahi, nh, kn); STAGE_B(Bhi, nh, kn); }
        #pragma unroll
        for (int mi = 0; mi < 8; ++mi)
            ah[mi] = *(const bf16x8*)(sh + aoff + mi * 512);
        #pragma unroll
        for (int nj = 0; nj < 3; ++nj)
            bh[nj] = *(const bf16x8*)(sh + boff + nj * 512);
        __builtin_amdgcn_s_setprio(1);
        #pragma unroll
        for (int mi = 0; mi < 8; ++mi)
            #pragma unroll
            for (int nj = 0; nj < 3; ++nj)
                acc[mi][nj] = __builtin_amdgcn_mfma_f32_16x16x32_bf16(
                    ah[mi], bh[nj], acc[mi][nj], 0, 0, 0);
        __builtin_amdgcn_s_setprio(0);

        // ---- ph2: lo slot valid
        if (kt < 31) { VMCNT(4); } else { VMCNT(0); }
        BAR;
        if (kt < 31) { STAGE_A(Alo, nl, kn); STAGE_B(Blo, nl, kn); }
        #pragma unroll
        for (int nj = 0; nj < 3; ++nj)
            bl[nj] = *(const bf16x8*)(sl + boff + nj * 512);
        #pragma unroll
        for (int mi = 0; mi < 8; ++mi)
            al[mi] = *(const bf16x8*)(sl + aoff + mi * 512);
        __builtin_amdgcn_s_setprio(1);
        #pragma unroll
        for (int mi = 0; mi < 8; ++mi)
            #pragma unroll
            for (int nj = 0; nj < 3; ++nj)
                acc[mi][nj] = __builtin_amdgcn_mfma_f32_16x16x32_bf16(
                    ah[mi], bl[nj], acc[mi][nj], 0, 0, 0);
        __builtin_amdgcn_s_setprio(0);

        // ---- ph3: register-only
        __builtin_amdgcn_s_setprio(1);
        #pragma unroll
        for (int mi = 0; mi < 8; ++mi)
            #pragma unroll
            for (int nj = 0; nj < 3; ++nj)
                acc[mi][nj] = __builtin_amdgcn_mfma_f32_16x16x32_bf16(
                    al[mi], bh[nj], acc[mi][nj], 0, 0, 0);
        __builtin_amdgcn_s_setprio(0);
    }
    #undef STAGE_A
    #undef STAGE_B

    const int erow  = m0 + wr * 128 + (lane >> 4) * 4;
    const int ecol0 = n0 + wc * 48 + frow;
    #pragma unroll
    for (int mi = 0; mi < 8; ++mi) {
        #pragma unroll
        for (int j = 0; j < 4; ++j) {
            const int row = erow + mi * 16 + j;
            #pragma unroll
            for (int nj = 0; nj < 3; ++nj) {
                const int col = ecol0 + nj * 16;
                float v = acc[mi][nj][j];
                if (col < 2048) v = elu1(v);
                dst[(size_t)row * 3072 + col] = v;
            }
        }
    }
}

// ---------------------------------------------------------------------------
// GEMM2: out = O1 @ Wo^T + bo. 128x128 tile, BK=32, 4 waves (2x2, 64x64/wave),
// 3-phase / 2-barrier-per-kt, no manual lgkm fence. Grid 256, 64KB LDS.
// ---------------------------------------------------------------------------
__global__ __launch_bounds__(256, 2)
void gemm2_mfma_kernel(const ushort* __restrict__ Ahi, const ushort* __restrict__ Alo,
                       const ushort* __restrict__ Bhi, const ushort* __restrict__ Blo,
                       const float* __restrict__ bias, float* __restrict__ dst)
{
    __shared__ ushort smem[4 * SLOT2_EL];   // 64 KB

    const int bid = blockIdx.x;
    const int wg  = (bid & 7) * 32 + (bid >> 3);    // bijective: 256 = 8*32
    const int m0  = (wg >> 3) * 128;                // 32 m-tiles
    const int n0  = (wg & 7) * 128;                 // 8 n-tiles

    const int t    = threadIdx.x;
    const int lane = t & 63;
    const int w    = t >> 6;      // 0..3
    const int wr   = w >> 1;      // 0..1
    const int wc   = w & 1;       // 0..1

    const int gch     = (t & 3) ^ ((t >> 3) & 3);
    const size_t rowA = (size_t)(m0 + (t >> 2)) * KDIM + gch * 8;
    const size_t rowB = (size_t)(n0 + (t >> 2)) * KDIM + gch * 8;
    const int wl      = w * 512;

    const int frow = lane & 15;
    const int cc   = (lane >> 4) ^ ((lane >> 1) & 3);
    const int aoff = (wr * 64 + frow) * 32 + cc * 8;
    const int boff = 4096 + (wc * 64 + frow) * 32 + cc * 8;

    f32x4 acc[4][4];
    #pragma unroll
    for (int mi = 0; mi < 4; ++mi)
        #pragma unroll
        for (int nj = 0; nj < 4; ++nj)
            acc[mi][nj] = (f32x4){0.f, 0.f, 0.f, 0.f};

    #define G2A(src, slotp, koff)                                            \
        do {                                                                 \
            ushort* p_ = (slotp);                                            \
            gl16((src) + rowA + (koff),         p_ + wl);                    \
            gl16((src) + rowA + 65536 + (koff), p_ + 2048 + wl);             \
        } while (0)
    #define G2B(src, slotp, koff)                                            \
        do {                                                                 \
            ushort* p_ = (slotp);                                            \
            gl16((src) + rowB + (koff),         p_ + 4096 + wl);             \
            gl16((src) + rowB + 65536 + (koff), p_ + 6144 + wl);             \
        } while (0)

    G2A(Ahi, smem, 0);
    G2B(Bhi, smem, 0);
    G2A(Alo, smem + SLOT2_EL, 0);
    G2B(Blo, smem + SLOT2_EL, 0);

    #pragma unroll 1
    for (int kt = 0; kt < 32; ++kt) {
        ushort* sh = smem + ((kt & 1) << 1) * SLOT2_EL;
        ushort* sl = sh + SLOT2_EL;
        ushort* nh = smem + ((2 * kt + 2) & 3) * SLOT2_EL;
        ushort* nl = smem + ((2 * kt + 3) & 3) * SLOT2_EL;
        const int kn = (kt + 1) * 32;

        bf16x8 ah[4], bh[4], bl[4], al[4];

        // ---- ph1: hh
        VMCNT(4);
        BAR;
        if (kt < 31) { G2A(Ahi, nh, kn); G2B(Bhi, nh, kn); }
        #pragma unroll
        for (int mi = 0; mi < 4; ++mi)
            ah[mi] = *(const bf16x8*)(sh + aoff + mi * 512);
        #pragma unroll
        for (int nj = 0; nj < 4; ++nj)
            bh[nj] = *(const bf16x8*)(sh + boff + nj * 512);
        __builtin_amdgcn_s_setprio(1);
        #pragma unroll
        for (int mi = 0; mi < 4; ++mi)
            #pragma unroll
            for (int nj = 0; nj < 4; ++nj)
                acc[mi][nj] = __builtin_amdgcn_mfma_f32_16x16x32_bf16(
                    ah[mi], bh[nj], acc[mi][nj], 0, 0, 0);
        __builtin_amdgcn_s_setprio(0);

        // ---- ph2: hl
        if (kt < 31) { VMCNT(4); } else { VMCNT(0); }
        BAR;
        if (kt < 31) { G2A(Alo, nl, kn); G2B(Blo, nl, kn); }
        #pragma unroll
        for (int nj = 0; nj < 4; ++nj)
            bl[nj] = *(const bf16x8*)(sl + boff + nj * 512);
        #pragma unroll
        for (int mi = 0; mi < 4; ++mi)
            al[mi] = *(const bf16x8*)(sl + aoff + mi * 512);
        __builtin_amdgcn_s_setprio(1);
        #pragma unroll
        for (int mi = 0; mi < 4; ++mi)
            #pragma unroll
            for (int nj = 0; nj < 4; ++nj)
                acc[mi][nj] = __builtin_amdgcn_mfma_f32_16x16x32_bf16(
                    ah[mi], bl[nj], acc[mi][nj], 0, 0, 0);
        __builtin_amdgcn_s_setprio(0);

        // ---- ph3: lh (register-only)
        __builtin_amdgcn_s_setprio(1);
        #pragma unroll
        for (int mi = 0; mi < 4; ++mi)
            #pragma unroll
            for (int nj = 0; nj < 4; ++nj)
                acc[mi][nj] = __builtin_amdgcn_mfma_f32_16x16x32_bf16(
                    al[mi], bh[nj], acc[mi][nj], 0, 0, 0);
        __builtin_amdgcn_s_setprio(0);
    }
    #undef G2A
    #undef G2B

    const int erow  = m0 + wr * 64 + (lane >> 4) * 4;
    const int ecol0 = n0 + wc * 64 + frow;
    #pragma unroll
    for (int mi = 0; mi < 4; ++mi) {
        #pragma unroll
        for (int j = 0; j < 4; ++j) {
            const int row = erow + mi * 16 + j;
            #pragma unroll
            for (int nj = 0; nj < 4; ++nj) {
                const int col = ecol0 + nj * 16;
                dst[(size_t)row * 1024 + col] = acc[mi][nj][j] + bias[col];
            }
        }
    }
}

// ---------------------------------------------------------------------------
// Partial KV = K_feat^T V and ksum, per (b,h), 8-way N split (256 rows each).
// ---------------------------------------------------------------------------
__global__ __launch_bounds__(256)
void kv_partial_kernel(const float* __restrict__ QKV, float* __restrict__ KVp)
{
    const int bh = blockIdx.x;   // 0..31
    const int s  = blockIdx.y;   // 0..7
    const int b  = bh >> 4;
    const int h  = bh & 15;
    const int t  = threadIdx.x;

    __shared__ float ks[16][64];
    __shared__ float vs[16][64];
    __shared__ float red[4160];

    const int srow = t >> 4;
    const int scol = (t & 15) * 4;
    const size_t gk = (size_t)(b * N_SEQ + s * 256) * 3072 + 1024 + h * 64 + scol;
    const size_t gv = gk + 1024;

    const int rs = t >> 6;
    const int dg = (t >> 3) & 7;
    const int eg = t & 7;
    const int d0 = dg * 8;
    const int e0 = eg * 8;

    float acc[8][8];
    #pragma unroll
    for (int i = 0; i < 8; ++i)
        #pragma unroll
        for (int j = 0; j < 8; ++j) acc[i][j] = 0.f;
    float aks[8] = {0.f, 0.f, 0.f, 0.f, 0.f, 0.f, 0.f, 0.f};

    float4 kr = *(const float4*)&QKV[gk + (size_t)srow * 3072];
    float4 vr = *(const float4*)&QKV[gv + (size_t)srow * 3072];

    for (int it = 0; it < 16; ++it) {
        __syncthreads();
        *(float4*)&ks[srow][scol] = kr;
        *(float4*)&vs[srow][scol] = vr;
        __syncthreads();
        if (it < 15) {
            kr = *(const float4*)&QKV[gk + (size_t)((it + 1) * 16 + srow) * 3072];
            vr = *(const float4*)&QKV[gv + (size_t)((it + 1) * 16 + srow) * 3072];
        }
        #pragma unroll
        for (int rr = 0; rr < 4; ++rr) {
            const int r = rs * 4 + rr;
            const float4 ka = *(const float4*)&ks[r][d0];
            const float4 kb = *(const float4*)&ks[r][d0 + 4];
            const float4 va = *(const float4*)&vs[r][e0];
            const float4 vb = *(const float4*)&vs[r][e0 + 4];
            const float k8[8] = {ka.x, ka.y, ka.z, ka.w, kb.x, kb.y, kb.z, kb.w};
            const float v8[8] = {va.x, va.y, va.z, va.w, vb.x, vb.y, vb.z, vb.w};
            #pragma unroll
            for (int i = 0; i < 8; ++i)
                #pragma unroll
                for (int j = 0; j < 8; ++j)
                    acc[i][j] += k8[i] * v8[j];
            if (eg == 0) {
                #pragma unroll
                for (int i = 0; i < 8; ++i) aks[i] += k8[i];
            }
        }
    }

    #pragma unroll 1
    for (int step = 1; step < 4; ++step) {
        __syncthreads();
        if (rs == step) {
            #pragma unroll
            for (int i = 0; i < 8; ++i)
                #pragma unroll
                for (int j = 0; j < 8; ++j)
                    red[(d0 + i) * 64 + e0 + j] = acc[i][j];
            if (eg == 0) {
                #pragma unroll
                for (int i = 0; i < 8; ++i) red[4096 + d0 + i] = aks[i];
            }
        }
        __syncthreads();
        if (rs == 0) {
            #pragma unroll
            for (int i = 0; i < 8; ++i)
                #pragma unroll
                for (int j = 0; j < 8; ++j)
                    acc[i][j] += red[(d0 + i) * 64 + e0 + j];
            if (eg == 0) {
                #pragma unroll
                for (int i = 0; i < 8; ++i) aks[i] += red[4096 + d0 + i];
            }
        }
    }

    if (rs == 0) {
        float* outp = KVp + ((size_t)s * 32 + bh) * 4160;
        #pragma unroll
        for (int i = 0; i < 8; ++i) {
            float4 o0 = {acc[i][0], acc[i][1], acc[i][2], acc[i][3]};
            float4 o1 = {acc[i][4], acc[i][5], acc[i][6], acc[i][7]};
            *(float4*)(outp + (d0 + i) * 64 + e0)     = o0;
            *(float4*)(outp + (d0 + i) * 64 + e0 + 4) = o1;
        }
        if (eg == 0) {
            #pragma unroll
            for (int i = 0; i < 8; ++i) outp[4096 + d0 + i] = aks[i];
        }
    }
}

__global__ __launch_bounds__(256)
void kv_reduce_kernel(const float* __restrict__ KVp, float* __restrict__ KVf)
{
    const int idx = blockIdx.x * 256 + threadIdx.x;
    if (idx < 32 * 4160) {
        float s = 0.f;
        #pragma unroll
        for (int i = 0; i < 8; ++i) s += KVp[(size_t)i * (32 * 4160) + idx];
        KVf[idx] = s;
    }
}

// ---------------------------------------------------------------------------
// O1[n, h*64+e] = Z * sum_d q[n,d]*KV[d,e], Z = 1/(q.ksum + 1e-6); bf16 hi/lo out
// ---------------------------------------------------------------------------
__global__ __launch_bounds__(256)
void attn_apply_kernel(const float* __restrict__ QKV, const float* __restrict__ KVf,
                       ushort* __restrict__ O1hi, ushort* __restrict__ O1lo)
{
    const int bh = blockIdx.x;
    const int b = bh >> 4, h = bh & 15;
    const int n0 = blockIdx.y * 16;
    const int t = threadIdx.x;
    const int r  = t >> 4;
    const int e0 = (t & 15) * 4;

    __shared__ float kvs[64][68];
    __shared__ float qs[16][68];
    __shared__ float ksums[64];

    const float* kvb = KVf + (size_t)bh * 4160;
    for (int i = t; i < 4096; i += 256)
        kvs[i >> 6][i & 63] = kvb[i];
    if (t < 64) ksums[t] = kvb[4096 + t];
    {
        const int rr = t >> 4, cc2 = (t & 15) * 4;
        *(float4*)&qs[rr][cc2] =
            *(const float4*)&QKV[(size_t)(b * N_SEQ + n0 + rr) * 3072 + h * 64 + cc2];
    }
    __syncthreads();

    float4 acc = {0.f, 0.f, 0.f, 0.f};
    float accz = 0.f;
    #pragma unroll
    for (int d = 0; d < 64; ++d) {
        const float qv = qs[r][d];
        const float4 kvv = *(const float4*)&kvs[d][e0];
        acc.x += qv * kvv.x; acc.y += qv * kvv.y;
        acc.z += qv * kvv.z; acc.w += qv * kvv.w;
        accz += qv * ksums[d];
    }
    const float Z = 1.f / (accz + 1e-6f);
    const float vv[4] = {acc.x * Z, acc.y * Z, acc.z * Z, acc.w * Z};
    ushort hv[4], lv[4];
    #pragma unroll
    for (int j = 0; j < 4; ++j) {
        hv[j] = f2bf(vv[j]);
        lv[j] = f2bf(vv[j] - bf2f(hv[j]));
    }
    const size_t off = (size_t)(b * N_SEQ + n0 + r) * C_DIM + h * 64 + e0;
    short4v H = {(short)hv[0], (short)hv[1], (short)hv[2], (short)hv[3]};
    short4v L = {(short)lv[0], (short)lv[1], (short)lv[2], (short)lv[3]};
    *(short4v*)&O1hi[off] = H;
    *(short4v*)&O1lo[off] = L;
}

extern "C" void kernel_launch(void* const* d_in, const int* in_sizes, int n_in,
                              void* d_out, int out_size, void* d_ws, size_t ws_size,
                              hipStream_t stream)
{
    const float* x   = (const float*)d_in[0];
    const float* Wq  = (const float*)d_in[1];
    const float* Wkv = (const float*)d_in[2];
    const float* Wo  = (const float*)d_in[3];
    const float* bo  = (const float*)d_in[4];
    float* out = (float*)d_out;

    float* ws   = (float*)d_ws;
    float* QKV  = ws;                                  // 4096*3072 f32
    float* KVp  = QKV + (size_t)M_ROWS * 3072;         // 8*32*4160
    float* KVf  = KVp + (size_t)8 * 32 * 4160;         // 32*4160
    ushort* xhi = (ushort*)(KVf + 32 * 4160);          // 4096*1024 bf16 each
    ushort* xlo = xhi + (size_t)M_ROWS * 1024;
    ushort* Whi = xlo + (size_t)M_ROWS * 1024;         // 3072*1024 (Wq;Wkv)
    ushort* Wlo = Whi + (size_t)3072 * 1024;
    ushort* Wohi = Wlo + (size_t)3072 * 1024;          // 1024*1024
    ushort* Wolo = Wohi + (size_t)1024 * 1024;
    ushort* O1hi = xhi;                                // alias: x dead after GEMM1
    ushort* O1lo = xlo;

    hipFuncSetAttribute((const void*)gemm1_mfma256_kernel,
                        hipFuncAttributeMaxDynamicSharedMemorySize, 131072);

    // 0. split fp32 -> bf16 hi/lo
    split_all_kernel<<<dim3(4096), 256, 0, stream>>>(
        x, Wq, Wkv, Wo, xhi, xlo, Whi, Wlo, Wohi, Wolo);

    // 1. fused q/k/v projections + elu+1 on q,k
    gemm1_mfma256_kernel<<<dim3(256), 512, 131072, stream>>>(xhi, xlo, Whi, Wlo, QKV);

    // 2-3. KV = K^T V + ksum (8-way split + deterministic reduce)
    kv_partial_kernel<<<dim3(32, 8), 256, 0, stream>>>(QKV, KVp);
    kv_reduce_kernel<<<dim3((32 * 4160 + 255) / 256), 256, 0, stream>>>(KVp, KVf);

    // 4. O1 = Z * (q @ KV), bf16 hi/lo out
    attn_apply_kernel<<<dim3(32, 128), 256, 0, stream>>>(QKV, KVf, O1hi, O1lo);

    // 5. final projection + bias
    gemm2_mfma_kernel<<<dim3(256), 256, 0, stream>>>(O1hi, O1lo, Wohi, Wolo, bo, out);
}